// Round 14
// baseline (158.951 us; speedup 1.0000x reference)
//
#include <hip/hip_runtime.h>
#include <math.h>

namespace {

constexpr int   kB     = 16;
constexpr int   kA     = 65536;
constexpr int   kM     = 32;
constexpr int   kC     = 20;
constexpr float kImg   = 600.0f;
constexpr int   kBlock = 256;

constexpr int kAnchPerThread = 4;
constexpr int kAnchPerBlock  = kBlock * kAnchPerThread;  // 1024
constexpr int kGridX         = kA / kAnchPerBlock;       // 64
constexpr int kNBlocks       = kGridX * kB;              // 1024 (ws: 1024*3 floats)

__device__ __forceinline__ float smooth_l1(float d) {
    float ad = fabsf(d);
    return ad < 1.0f ? 0.5f * d * d : ad - 0.5f;
}

// f0(x) = sigmoid(x)^2 * softplus(x)  (t=0 focal term; t=1 is f0(-x)).
// Single definition everywhere -> stream/correction terms cancel exactly.
__device__ __forceinline__ float f0s(float x) {
    float u  = __expf(-x);
    float d  = 1.0f + u;
    float s  = __builtin_amdgcn_rcpf(d);       // sigmoid(x)
    float sp = x + __logf(d);                  // softplus(x)
    return s * s * sp;
}

// Lessons ledger:
//  R2: launch_bounds min-waves arg -> VGPR cap -> 359 MB spill. Avoid.
//  R4/R7/R8: role-split regalloc cliff; row bodies every wave; hot atomics.
//  R9->R10: LDS-read sharing across 4 anchors = only confirmed win (-6us).
//  R5/R6 (VALU cuts), R12 (coalescing), R13 (occupancy) all NEUTRAL ~43-45us.
//  R14 theory: PHASE-LOCKING. Homogeneous blocks march in lockstep: IoU phase
//      (LDS/VALU, HBM idle ~10us) then stream phase (HBM/trans, LDS idle
//      ~20us) -> serial sum ~43us. THIS round: odd blocks run stream-FIRST
//      (raw row sums rs[k], liveness applied after IoU), even blocks keep
//      R10 order -> at any instant half the machine uses HBM, half LDS/VALU.
__global__ __launch_bounds__(kBlock) void retina_main(
    const float* __restrict__ loc_preds,   // [B, A, 4]
    const float* __restrict__ cls_preds,   // [B, A, C]
    const float* __restrict__ iou_boxes,   // [A, 4] xywh
    const float* __restrict__ targets,     // [B*M, 6]
    float* __restrict__ partial)           // [kNBlocks][3]
{
    __shared__ float4 sbox[kM];    // x1, y1, x2+1, y2+1 (pixels)
    __shared__ float4 sxywh[kM];   // cx, cy, w, h (pixels)
    __shared__ float  sarea[kM];   // target area (+1 convention)
    __shared__ int    slab[kM];
    __shared__ float  sred[3][kBlock / 64];

    const int b   = blockIdx.y;
    const int ab  = blockIdx.x * kAnchPerBlock;
    const int tid = threadIdx.x;
    const int a0  = ab + tid;                 // thread's anchors: a0 + K*256
    const bool streamFirst = ((blockIdx.x + blockIdx.y) & 1) != 0;

    if (tid < kM) {
        const float* t = targets + ((size_t)(b * kM + tid)) * 6;
        float cx = t[2] * kImg, cy = t[3] * kImg;
        float w  = t[4] * kImg, h  = t[5] * kImg;
        float x1  = cx - w * 0.5f,        y1  = cy - h * 0.5f;
        float x2p = cx + w * 0.5f + 1.0f, y2p = cy + h * 0.5f + 1.0f;
        sbox[tid]  = make_float4(x1, y1, x2p, y2p);
        sxywh[tid] = make_float4(cx, cy, w, h);
        sarea[tid] = (x2p - x1) * (y2p - y1);
        slab[tid]  = (int)t[1];
    }

    // Anchor rows: issue early in both roles (consumed after the barrier).
    const float4 an0 = *(const float4*)(iou_boxes + (size_t)(a0 + 0 * kBlock) * 4);
    const float4 an1 = *(const float4*)(iou_boxes + (size_t)(a0 + 1 * kBlock) * 4);
    const float4 an2 = *(const float4*)(iou_boxes + (size_t)(a0 + 2 * kBlock) * 4);
    const float4 an3 = *(const float4*)(iou_boxes + (size_t)(a0 + 3 * kBlock) * 4);

    const float* rp = cls_preds + ((size_t)b * kA + a0) * kC;   // anchor a0's row

#define ROWLOAD(D0,D1,D2,D3,D4, KK) { \
    const float* p_ = rp + (size_t)(KK) * kBlock * kC; \
    D0 = *(const float4*)(p_ + 0); \
    D1 = *(const float4*)(p_ + 4); \
    D2 = *(const float4*)(p_ + 8); \
    D3 = *(const float4*)(p_ + 12); \
    D4 = *(const float4*)(p_ + 16); }

#define S20(A0,A1,A2,A3,A4) \
    (f0s(A0.x) + f0s(A0.y) + f0s(A0.z) + f0s(A0.w) + \
     f0s(A1.x) + f0s(A1.y) + f0s(A1.z) + f0s(A1.w) + \
     f0s(A2.x) + f0s(A2.y) + f0s(A2.z) + f0s(A2.w) + \
     f0s(A3.x) + f0s(A3.y) + f0s(A3.z) + f0s(A3.w) + \
     f0s(A4.x) + f0s(A4.y) + f0s(A4.z) + f0s(A4.w))

    float4 r0, r1, r2, r3, r4;
    float  rs0 = 0.0f, rs1 = 0.0f, rs2 = 0.0f, rs3 = 0.0f;

    if (streamFirst) {
        // ---- Stream phase FIRST: raw row sums, no mask (applied post-IoU) ----
        float4 n0, n1, n2, n3, n4;
        ROWLOAD(r0, r1, r2, r3, r4, 0)
        ROWLOAD(n0, n1, n2, n3, n4, 1)
        rs0 = S20(r0, r1, r2, r3, r4);
        ROWLOAD(r0, r1, r2, r3, r4, 2)
        rs1 = S20(n0, n1, n2, n3, n4);
        ROWLOAD(n0, n1, n2, n3, n4, 3)
        rs2 = S20(r0, r1, r2, r3, r4);
        rs3 = S20(n0, n1, n2, n3, n4);
    } else {
        // R10 prologue: row 0 in flight before the barrier, latency under IoU.
        ROWLOAD(r0, r1, r2, r3, r4, 0)
    }

    __syncthreads();

#define DERIVE(K, AN) \
    const float x1_##K = AN.x - AN.z * 0.5f; \
    const float y1_##K = AN.y - AN.w * 0.5f; \
    const float x2_##K = AN.x + AN.z * 0.5f + 1.0f; \
    const float y2_##K = AN.y + AN.w * 0.5f + 1.0f; \
    const float ar_##K = (x2_##K - x1_##K) * (y2_##K - y1_##K);
    DERIVE(0, an0) DERIVE(1, an1) DERIVE(2, an2) DERIVE(3, an3)
#undef DERIVE

    float bs0 = -1.0f, bs1 = -1.0f, bs2 = -1.0f, bs3 = -1.0f;
    int   m0 = 0, m1 = 0, m2 = 0, m3 = 0;

    // ---- IoU argmax: ONE sbox/sarea read serves FOUR anchors ----
#pragma unroll 8
    for (int m = 0; m < kM; ++m) {
        const float4 q  = sbox[m];
        const float  ar = sarea[m];
#define IOU(K) { \
        float lx = fmaxf(x1_##K, q.x); \
        float ly = fmaxf(y1_##K, q.y); \
        float rx = fminf(x2_##K, q.z); \
        float ry = fminf(y2_##K, q.w); \
        float w  = fmaxf(rx - lx, 0.0f); \
        float h  = fmaxf(ry - ly, 0.0f); \
        float inter = w * h; \
        float uni   = ar_##K + ar - inter; \
        float iou   = inter * __builtin_amdgcn_rcpf(uni); \
        if (iou > bs##K) { bs##K = iou; m##K = m; } }
        IOU(0) IOU(1) IOU(2) IOU(3)
#undef IOU
    }

    const bool pos0 = bs0 >= 0.5f, ign0 = (bs0 > 0.4f) && !pos0;
    const bool pos1 = bs1 >= 0.5f, ign1 = (bs1 > 0.4f) && !pos1;
    const bool pos2 = bs2 >= 0.5f, ign2 = (bs2 > 0.4f) && !pos2;
    const bool pos3 = bs3 >= 0.5f, ign3 = (bs3 > 0.4f) && !pos3;

    float loc_sum = 0.0f, cls_sum = 0.0f, npos = 0.0f;

    // pos handling (rare; exec-masked). Reloads what it needs (L1-hot).
#define POSFIX(K) \
    if (pos##K) { \
        npos += 1.0f; \
        const int ak = a0 + K * kBlock; \
        const float4 an = *(const float4*)(iou_boxes + (size_t)ak * 4); \
        const float4 lp = *(const float4*)(loc_preds + ((size_t)b * kA + ak) * 4); \
        const float4 mb = sxywh[m##K]; \
        float ltx = (mb.x - an.x) * __builtin_amdgcn_rcpf(an.z); \
        float lty = (mb.y - an.y) * __builtin_amdgcn_rcpf(an.w); \
        float ltw = __logf(mb.z * __builtin_amdgcn_rcpf(an.z)); \
        float lth = __logf(mb.w * __builtin_amdgcn_rcpf(an.w)); \
        loc_sum += smooth_l1(lp.x - ltx) + smooth_l1(lp.y - lty) + \
                   smooth_l1(lp.z - ltw) + smooth_l1(lp.w - lth); \
        const float xc = (rp + (size_t)K * kBlock * kC)[slab[m##K]]; \
        cls_sum += 0.25f * f0s(-xc) - 0.75f * f0s(xc); \
    }

    if (streamFirst) {
        // ---- Combine: liveness applied to the pre-computed raw row sums ----
        cls_sum += (ign0 ? 0.0f : 0.75f) * rs0;
        cls_sum += (ign1 ? 0.0f : 0.75f) * rs1;
        cls_sum += (ign2 ? 0.0f : 0.75f) * rs2;
        cls_sum += (ign3 ? 0.0f : 0.75f) * rs3;
        POSFIX(0) POSFIX(1) POSFIX(2) POSFIX(3)
    } else {
        // ---- R10 order: pipelined rows, liveness applied inline ----
        float4 n0, n1, n2, n3, n4;
        ROWLOAD(n0, n1, n2, n3, n4, 1)
        cls_sum += (ign0 ? 0.0f : 0.75f) * S20(r0, r1, r2, r3, r4);
        POSFIX(0)
        r0 = n0; r1 = n1; r2 = n2; r3 = n3; r4 = n4;

        ROWLOAD(n0, n1, n2, n3, n4, 2)
        cls_sum += (ign1 ? 0.0f : 0.75f) * S20(r0, r1, r2, r3, r4);
        POSFIX(1)
        r0 = n0; r1 = n1; r2 = n2; r3 = n3; r4 = n4;

        ROWLOAD(n0, n1, n2, n3, n4, 3)
        cls_sum += (ign2 ? 0.0f : 0.75f) * S20(r0, r1, r2, r3, r4);
        POSFIX(2)
        r0 = n0; r1 = n1; r2 = n2; r3 = n3; r4 = n4;

        cls_sum += (ign3 ? 0.0f : 0.75f) * S20(r0, r1, r2, r3, r4);
        POSFIX(3)
    }

#undef POSFIX
#undef S20
#undef ROWLOAD

    // ---- Reduce: wave shuffle -> LDS -> per-block partial (no atomics) ----
#pragma unroll
    for (int off = 32; off > 0; off >>= 1) {
        loc_sum += __shfl_down(loc_sum, off);
        cls_sum += __shfl_down(cls_sum, off);
        npos    += __shfl_down(npos, off);
    }
    const int lane = tid & 63;
    const int wid  = tid >> 6;
    if (lane == 0) {
        sred[0][wid] = loc_sum;
        sred[1][wid] = cls_sum;
        sred[2][wid] = npos;
    }
    __syncthreads();
    if (tid == 0) {
        float l = 0.0f, c = 0.0f, n = 0.0f;
#pragma unroll
        for (int i = 0; i < kBlock / 64; ++i) {
            l += sred[0][i]; c += sred[1][i]; n += sred[2][i];
        }
        const int bid = blockIdx.y * gridDim.x + blockIdx.x;
        partial[3 * bid + 0] = l;
        partial[3 * bid + 1] = c;
        partial[3 * bid + 2] = n;
    }
}

__global__ __launch_bounds__(1024) void retina_final(
    const float* __restrict__ partial, float* __restrict__ out)
{
    __shared__ float s[3][16];
    float l = 0.0f, c = 0.0f, n = 0.0f;
    for (int i = threadIdx.x; i < kNBlocks; i += 1024) {
        l += partial[3 * i + 0];
        c += partial[3 * i + 1];
        n += partial[3 * i + 2];
    }
#pragma unroll
    for (int off = 32; off > 0; off >>= 1) {
        l += __shfl_down(l, off);
        c += __shfl_down(c, off);
        n += __shfl_down(n, off);
    }
    const int lane = threadIdx.x & 63;
    const int wid  = threadIdx.x >> 6;
    if (lane == 0) { s[0][wid] = l; s[1][wid] = c; s[2][wid] = n; }
    __syncthreads();
    if (threadIdx.x == 0) {
        float L = 0.0f, C = 0.0f, N = 0.0f;
#pragma unroll
        for (int i = 0; i < 16; ++i) { L += s[0][i]; C += s[1][i]; N += s[2][i]; }
        float np  = fmaxf(1.0f, N);
        float inv = 1.0f / np;
        out[0] = (L + C) * inv;
        out[1] = L * inv;
        out[2] = C * inv;
    }
}

}  // namespace

extern "C" void kernel_launch(void* const* d_in, const int* in_sizes, int n_in,
                              void* d_out, int out_size, void* d_ws, size_t ws_size,
                              hipStream_t stream) {
    const float* loc_preds = (const float*)d_in[0];
    const float* cls_preds = (const float*)d_in[1];
    const float* iou_boxes = (const float*)d_in[2];
    const float* targets   = (const float*)d_in[3];
    float* out     = (float*)d_out;
    float* partial = (float*)d_ws;   // 1024*3 floats, fully overwritten each call

    dim3 grid(kGridX, kB);
    retina_main<<<grid, kBlock, 0, stream>>>(loc_preds, cls_preds, iou_boxes, targets, partial);
    retina_final<<<1, 1024, 0, stream>>>(partial, out);
}